// Round 1
// 211.872 us; speedup vs baseline: 1.0514x; 1.0514x over previous
//
#include <hip/hip_runtime.h>
#include <math.h>

#define NB 128
#define NT 512
#define NEDIM 128
#define NNEG 64
#define SCHUNK 16
#define NCHUNK (NT / SCHUNK)      // 32 chunks per batch row
#define NBLK (NB * NCHUNK)        // 4096 blocks
#define WSN (NBLK * 4)            // 16384 per-wave partials

typedef __bf16 bf16x8 __attribute__((ext_vector_type(8)));
typedef float  f32x4  __attribute__((ext_vector_type(4)));

// M = 64 rows: m = 4*sloc + (i-1), sloc = m>>2, ip = (m&3)+1.
// N = 96 cols: 0..63 negatives, 64+j = base row s0+1+j (j<19; j in [19,32) zero).
// K = 128 (e), 4 ksteps of 32.
// Positives are computed BY THE MFMA (col 64+pcol, pcol = sloc+ip-1 in [0,18])
// and extracted from the C tile — no separate positives pass, no pos_lds,
// single __syncthreads in the whole kernel.
// LDS = 16 KiB (A) + 24 KiB (B) = 40 KiB exactly -> 4 blocks/CU.
__launch_bounds__(256, 4)
__global__ void cpc_mfma_kernel(const float* __restrict__ base,        // (B,T,E)
                                const float* __restrict__ mce,         // (B,T,E,K)
                                const int*  __restrict__ seq_lens,     // (B)
                                const int*  __restrict__ sample_ids,   // (B,NNEG)
                                float* __restrict__ ws)                // (WSN)
{
    const int b    = blockIdx.y;
    const int s0   = blockIdx.x * SCHUNK;
    const int slot = (b * NCHUNK + blockIdx.x) * 4;
    const int L    = seq_lens[b];
    const float LOG65 = 4.1743873f;
    const float wgt[4] = {1.f/261632.f, 1.f/261120.f, 1.f/260608.f, 1.f/260096.f};

    // Fully-masked chunk: all-zero ce rows give loss = ln(65) analytically.
    if (s0 >= L) {
        if (threadIdx.x < 4) {
            float c = 0.f;
            #pragma unroll
            for (int i = 1; i <= 4; ++i) {
                int hi = min(SCHUNK, (NT - i) - s0);
                if (hi > 0) c += (float)hi * LOG65 * wgt[i - 1];
            }
            ws[slot + threadIdx.x] = (threadIdx.x == 0) ? c : 0.f;
        }
        return;
    }

    __shared__ __bf16 Afrag[1024 * 8];   // 16 KiB: 1024 chunks x 16B, xor-swizzled
    __shared__ __bf16 Bfrag[1536 * 8];   // 24 KiB: 16 e-blocks x 96 cols, ^(eb&7)

    const int tid  = threadIdx.x;
    const int lane = tid & 63;
    const int w    = tid >> 6;
    const int q    = lane >> 4;
    const int fl   = lane & 15;

    const float4* mce4 = (const float4*)mce;   // (b*NT+s)*NEDIM + e -> 4 k values

    // ---- stage A: transpose k->row, f32->bf16, fragment-linear chunks ----
    // chunk = (kstep*4 + mt)*64 + q*16 + flm ; phys = chunk ^ (Cs&7)
    {
        int s  = tid & 15;                 // s-inner: keeps write banks spread
        int eb = tid >> 4;                 // e0 = eb*8
        const float4* src = mce4 + (size_t)(b * NT + s0 + s) * NEDIM + eb * 8;
        float4 v[8];
        #pragma unroll
        for (int u = 0; u < 8; ++u) v[u] = src[u];
        const float* vf = (const float*)v;
        int Cs = (eb >> 2) * 4 + (s >> 2);
        int base_chunk = Cs * 64 + (eb & 3) * 16 + (s & 3) * 4;
        int x = Cs & 7;
        #pragma unroll
        for (int k = 0; k < 4; ++k) {
            int phys = (base_chunk + k) ^ x;
            bf16x8 o;
            #pragma unroll
            for (int u = 0; u < 8; ++u) o[u] = (__bf16)vf[4 * u + k];
            *(bf16x8*)(&Afrag[phys * 8]) = o;
        }
    }

    // ---- stage B: negatives, row-contiguous 16-lane groups (coalesced) ----
    #pragma unroll
    for (int it = 0; it < 4; ++it) {
        int h  = tid + 256 * it;          // 0..1023 : (n, eb)
        int n  = h >> 4;
        int eb = h & 15;
        int r  = sample_ids[b * NNEG + n];
        const float4* srcb = (const float4*)(base + (size_t)r * NEDIM);
        float4 v0 = srcb[eb * 2], v1 = srcb[eb * 2 + 1];
        const float* f0 = (const float*)&v0;
        const float* f1 = (const float*)&v1;
        bf16x8 o;
        #pragma unroll
        for (int u = 0; u < 4; ++u) { o[u] = (__bf16)f0[u]; o[4 + u] = (__bf16)f1[u]; }
        int phys = (eb * 96 + n) ^ (eb & 7);
        *(bf16x8*)(&Bfrag[phys * 8]) = o;
    }

    // ---- stage B: positive rows s0+1+j, j in [0,19); pad cols [19,32) zero ----
    #pragma unroll
    for (int it = 0; it < 2; ++it) {
        int h  = tid + 256 * it;          // 0..511 : (j, eb)
        int j  = h >> 4;
        int eb = h & 15;
        bf16x8 o;
        #pragma unroll
        for (int u = 0; u < 8; ++u) o[u] = (__bf16)0.f;
        if (j < SCHUNK + 3) {
            int srow = s0 + 1 + j; if (srow > NT - 1) srow = NT - 1;  // clamped rows feed only non-taken rows
            const float4* srcp = (const float4*)(base + (size_t)(b * NT + srow) * NEDIM);
            float4 v0 = srcp[eb * 2], v1 = srcp[eb * 2 + 1];
            const float* f0 = (const float*)&v0;
            const float* f1 = (const float*)&v1;
            #pragma unroll
            for (int u = 0; u < 4; ++u) { o[u] = (__bf16)f0[u]; o[4 + u] = (__bf16)f1[u]; }
        }
        int phys = (eb * 96 + 64 + j) ^ (eb & 7);
        *(bf16x8*)(&Bfrag[phys * 8]) = o;
    }
    __syncthreads();

    // ---- MFMA: wave w owns M-tile w x 6 N-tiles (4 neg + 2 pos) ----
    f32x4 acc[6];
    #pragma unroll
    for (int nt = 0; nt < 6; ++nt) acc[nt] = (f32x4){0.f, 0.f, 0.f, 0.f};

    #pragma unroll
    for (int kstep = 0; kstep < 4; ++kstep) {
        int CsA = kstep * 4 + w;
        bf16x8 af = *(const bf16x8*)(&Afrag[((CsA * 64 + lane) ^ (CsA & 7)) * 8]);
        int ebB = kstep * 4 + q;
        int xb  = ebB & 7;
        bf16x8 bv[6];
        #pragma unroll
        for (int nt = 0; nt < 6; ++nt)
            bv[nt] = *(const bf16x8*)(&Bfrag[((ebB * 96 + nt * 16 + fl) ^ xb) * 8]);
        #pragma unroll
        for (int nt = 0; nt < 6; ++nt)
            acc[nt] = __builtin_amdgcn_mfma_f32_16x16x32_bf16(af, bv[nt], acc[nt], 0, 0, 0);
    }

    // ---- epilogue: extract positive from C, logsumexp over 65, masked mean ----
    const int sloc = w * 4 + q;           // = m>>2 for this thread's rows
    const int sg   = s0 + sloc;
    float lossacc = 0.f;
    #pragma unroll
    for (int r = 0; r < 4; ++r) {
        int ip   = r + 1;                 // m&3 == r
        int pcol = sloc + r;              // positive column within pos tiles
        float z0 = acc[0][r], z1 = acc[1][r];
        float z2 = acc[2][r], z3 = acc[3][r];
        float pv = (pcol < 16) ? acc[4][r] : acc[5][r];   // tile index compile-time
        float p  = __shfl(pv, (lane & 48) | (pcol & 15)); // grab col pcol's lane
        float mx = fmaxf(fmaxf(z0, z1), fmaxf(z2, z3));
        mx = fmaxf(mx, __shfl_xor(mx, 1));
        mx = fmaxf(mx, __shfl_xor(mx, 2));
        mx = fmaxf(mx, __shfl_xor(mx, 4));
        mx = fmaxf(mx, __shfl_xor(mx, 8));
        mx = fmaxf(mx, p);
        float es = __expf(z0 - mx) + __expf(z1 - mx)
                 + __expf(z2 - mx) + __expf(z3 - mx);
        es += __shfl_xor(es, 1);
        es += __shfl_xor(es, 2);
        es += __shfl_xor(es, 4);
        es += __shfl_xor(es, 8);
        es += __expf(p - mx);
        float loss = __logf(es) + (mx - p);
        loss = (sg < L) ? loss : LOG65;            // masked row => ln(65)
        bool take = (sg < NT - ip) && (fl == 0);   // valid (s,i); one lane per row
        lossacc += take ? wgt[r] * loss : 0.f;
    }
    lossacc += __shfl_xor(lossacc, 16);
    lossacc += __shfl_xor(lossacc, 32);
    if (lane == 0) ws[slot + w] = lossacc;         // per-wave partial; no barrier
}

// Sum the 16384 per-wave partials -> out[0]. One block, no atomics.
__global__ void reduce_k(const float* __restrict__ ws, float* __restrict__ out) {
    const int tid = threadIdx.x;   // 256
    float s = 0.f;
    #pragma unroll
    for (int i = 0; i < WSN / 256; ++i) s += ws[tid + 256 * i];
    s += __shfl_xor(s, 1);
    s += __shfl_xor(s, 2);
    s += __shfl_xor(s, 4);
    s += __shfl_xor(s, 8);
    s += __shfl_xor(s, 16);
    s += __shfl_xor(s, 32);
    __shared__ float wsum[4];
    if ((tid & 63) == 0) wsum[tid >> 6] = s;
    __syncthreads();
    if (tid == 0) out[0] = wsum[0] + wsum[1] + wsum[2] + wsum[3];
}

extern "C" void kernel_launch(void* const* d_in, const int* in_sizes, int n_in,
                              void* d_out, int out_size, void* d_ws, size_t ws_size,
                              hipStream_t stream) {
    (void)in_sizes; (void)n_in; (void)out_size; (void)ws_size;
    const float* base       = (const float*)d_in[0];
    const float* mce        = (const float*)d_in[1];
    const int*   seq_lens   = (const int*)d_in[2];
    const int*   sample_ids = (const int*)d_in[3];
    float* out = (float*)d_out;
    float* ws  = (float*)d_ws;   // 16384 floats; every wave writes its slot

    dim3 grid(NCHUNK, NB);
    cpc_mfma_kernel<<<grid, 256, 0, stream>>>(base, mce, seq_lens, sample_ids, ws);
    reduce_k<<<1, 256, 0, stream>>>(ws, out);
}